// Round 4
// baseline (331.348 us; speedup 1.0000x reference)
//
#include <hip/hip_runtime.h>
#include <stdint.h>

#define NPTS  8192
#define NB    4
#define KNN   20
#define NROWS (NB * NPTS)        // 32768
#define MTOTF 655360.0f          // NROWS * KNN
#define CL    16                 // candidate lanes per row
#define RW    4                  // rows per wave
#define WPB   4                  // waves per block
#define BLK   256
#define RPB   (WPB * RW)         // 16 rows per block
#define STEPS (NPTS / CL)        // 512
#define LSTR  (KNN + 1)          // padded LDS list stride
#define ACCN  32                 // spread accumulator slots (pairs)
#define FINF  3.0e38f

__device__ __forceinline__ float med3f(float a, float b, float c) {
    return __builtin_amdgcn_fmed3f(a, b, c);
}

// One wave = 4 rows x 16 candidate-lanes. Each lane keeps the top-20 smallest
// d2 of its 512-candidate stream; the med3 insert chain runs only when ANY
// lane's d2 beats tau (tau = group-min of per-lane 20th-smallest, a provable
// upper bound on the row's final 20th-smallest -> skipping d2 >= tau is safe;
// in-wave no-op inserts are idempotent).
__global__ __launch_bounds__(BLK, 8) void knn_kernel(
    const float* __restrict__ x,
    float* __restrict__ kmaxA, float* __restrict__ kminA, float* __restrict__ acc)
{
    __shared__ float lists[BLK * LSTR];   // 21504 B
    __shared__ float ssum[RPB * 2];

    const int tid  = threadIdx.x;
    const int lane = tid & 63;
    const int wave = tid >> 6;
    const int c16  = lane & (CL - 1);
    const int r4   = lane >> 4;                 // 0..3 (row within wave)
    const int rowInBlk = wave * RW + r4;
    const int row  = blockIdx.x * RPB + rowInBlk;
    const int b    = row >> 13;                 // 512 blocks per batch, aligned
    const int n    = row & (NPTS - 1);
    const float* xb = x + b * 3 * NPTS;

    const float px = xb[n];
    const float py = xb[NPTS + n];
    const float pz = xb[2 * NPTS + n];

    float arr[KNN];                             // ascending d2
#pragma unroll
    for (int j = 0; j < KNN; ++j) arr[j] = FINF;

    const float* cx = xb + c16;                 // lane's candidate stream, stride CL
    float nqx = cx[0], nqy = cx[NPTS], nqz = cx[2 * NPTS];
    float tau = FINF;

    for (int s = 0; s < STEPS; ++s) {
        const float qx = nqx, qy = nqy, qz = nqz;
        const int nc = ((s + 1) & (STEPS - 1)) * CL;   // wrap avoids OOB; value unused at last step
        nqx = cx[nc]; nqy = cx[nc + NPTS]; nqz = cx[nc + 2 * NPTS];
        const float dx = qx - px, dy = qy - py, dz = qz - pz;
        const float d2 = fmaf(dx, dx, fmaf(dy, dy, dz * dz));
        if (__any(d2 < tau)) {
            // branchless sorted insert (ascending), drop largest
#pragma unroll
            for (int j = KNN - 1; j > 0; --j) arr[j] = med3f(d2, arr[j - 1], arr[j]);
            arr[0] = fminf(arr[0], d2);
        }
        if ((s & 7) == 7) {                     // refresh tau (stale = looser = safe)
            float t = arr[KNN - 1];
#pragma unroll
            for (int m = 1; m < CL; m <<= 1) t = fminf(t, __shfl_xor(t, m, 64));
            tau = t;
        }
    }

    // ---- merge 16 sorted lane-lists per row by parallel extraction ----
    float* my = lists + tid * LSTR;
#pragma unroll
    for (int j = 0; j < KNN; ++j) my[j] = arr[j];   // own-lane readback only; no barrier needed

    const unsigned long long gmask = 0xFFFFull << (r4 * 16);
    int pos = 0;
    float sum = 0.f, sum2 = 0.f, dmin = 0.f, dlast = 0.f;
    for (int k = 0; k < KNN; ++k) {
        const float h = (pos < KNN) ? my[pos] : FINF;
        float g = h;
#pragma unroll
        for (int m = 1; m < CL; m <<= 1) g = fminf(g, __shfl_xor(g, m, 64));
        const unsigned long long msk = __ballot(h == g) & gmask;  // nonzero: some in-group lane holds g
        if (lane == (int)__builtin_ctzll(msk)) pos++;             // one lane advances on ties
        const float d = sqrtf(g);
        sum += d; sum2 += g;
        if (k == 0) dmin = d;
        dlast = d;                                                 // k=19 -> 20th smallest
    }
    if (c16 == 0) {
        kmaxA[row] = dlast;
        kminA[row] = dmin;
        ssum[rowInBlk * 2]     = sum;
        ssum[rowInBlk * 2 + 1] = sum2;
    }
    __syncthreads();
    if (tid == 0) {
        float S = 0.f, S2 = 0.f;
#pragma unroll
        for (int r = 0; r < RPB; ++r) { S += ssum[r * 2]; S2 += ssum[r * 2 + 1]; }
        const int slot = (int)(blockIdx.x & (ACCN - 1));
        atomicAdd(acc + slot * 2,     S);
        atomicAdd(acc + slot * 2 + 1, S2);
    }
}

// out[b,c,n] = lrelu(a_c * (a_c>=0 ? kmax : kmin) + d_c); BN coefs computed
// inline from the spread accumulators (conv bias cancels inside BN).
__global__ __launch_bounds__(256) void out_kernel(
    const float* __restrict__ kmaxA, const float* __restrict__ kminA,
    const float* __restrict__ acc,
    const float* __restrict__ w, const float* __restrict__ gamma,
    const float* __restrict__ beta, float* __restrict__ out)
{
    const int r = blockIdx.x * 256 + threadIdx.x;   // 0..32767
    const int b = r >> 13;
    const int n = r & (NPTS - 1);
    float S = 0.f, S2 = 0.f;
#pragma unroll
    for (int i = 0; i < ACCN; ++i) { S += acc[2 * i]; S2 += acc[2 * i + 1]; }
    const float mu = S * (1.0f / MTOTF);
    float var = S2 * (1.0f / MTOTF) - mu * mu;
    var = fmaxf(var, 0.f);
    const float kmax = kmaxA[r];
    const float kmin = kminA[r];
#pragma unroll
    for (int c = 0; c < 16; ++c) {
        const float wc = w[c];
        const float a = gamma[c] * wc * rsqrtf(wc * wc * var + 1e-5f);
        const float d = beta[c] - a * mu;
        float v = a * (a >= 0.f ? kmax : kmin) + d;
        v = (v >= 0.f) ? v : 0.2f * v;
        out[(b * 16 + c) * NPTS + n] = v;
    }
}

extern "C" void kernel_launch(void* const* d_in, const int* in_sizes, int n_in,
                              void* d_out, int out_size, void* d_ws, size_t ws_size,
                              hipStream_t stream)
{
    const float* x     = (const float*)d_in[0];
    const float* w     = (const float*)d_in[1];
    const float* gamma = (const float*)d_in[3];
    const float* beta  = (const float*)d_in[4];
    float* out = (float*)d_out;
    float* ws  = (float*)d_ws;

    float* kmaxA = ws;                       // NROWS floats
    float* kminA = ws + NROWS;               // NROWS floats
    float* acc   = ws + 2 * NROWS;           // ACCN*2 floats

    hipMemsetAsync(acc, 0, ACCN * 2 * sizeof(float), stream);
    knn_kernel<<<NROWS / RPB, BLK, 0, stream>>>(x, kmaxA, kminA, acc);
    out_kernel<<<NROWS / 256, 256, 0, stream>>>(kmaxA, kminA, acc, w, gamma, beta, out);
}